// Round 1
// baseline (4455.571 us; speedup 1.0000x reference)
//
#include <hip/hip_runtime.h>

typedef short bf16x8 __attribute__((ext_vector_type(8)));
typedef float f32x4 __attribute__((ext_vector_type(4)));

#define MFMA16(a, b, c) __builtin_amdgcn_mfma_f32_16x16x32_bf16(a, b, c, 0, 0, 0)

#define B_ 1024
#define T_ 512
#define C_ 32
#define H_ 256
#define G_ 16   // batch samples per block -> 64 blocks

__device__ __forceinline__ unsigned short f2bf(float f) {
  union { float f; unsigned u; } v; v.f = f;
  return (unsigned short)((v.u + 0x7fffu + ((v.u >> 16) & 1u)) >> 16);
}

__device__ __forceinline__ float fsigmoid(float x) {
  float e = __builtin_amdgcn_exp2f(-1.442695041f * x);
  return __builtin_amdgcn_rcpf(1.0f + e);
}

__device__ __forceinline__ float ftanh(float x) {
  float e = __builtin_amdgcn_exp2f(2.885390082f * x);
  return 1.0f - 2.0f * __builtin_amdgcn_rcpf(e + 1.0f);
}

// ---------- preprocessing: pack W_cat = [Wih | Whh] to bf16, combine biases ----------
// encW/decW: [768][288] bf16 row-major (cols 0..31 = Wih, 32..287 = Whh)
// bias layout (f32): [0..255]=bih_r+bhh_r, [256..511]=bih_z+bhh_z,
//                    [512..767]=bih_n, [768..1023]=bhh_n
__global__ void pack_kernel(
    const float* __restrict__ encWih, const float* __restrict__ encWhh,
    const float* __restrict__ encbih, const float* __restrict__ encbhh,
    const float* __restrict__ decWih, const float* __restrict__ decWhh,
    const float* __restrict__ decbih, const float* __restrict__ decbhh,
    const float* __restrict__ projW, const float* __restrict__ projB,
    unsigned short* __restrict__ encW, unsigned short* __restrict__ decW,
    unsigned short* __restrict__ pW, float* __restrict__ encBias,
    float* __restrict__ decBias, float* __restrict__ pB) {
  int i = blockIdx.x * 256 + threadIdx.x;
  if (i < 768 * 288) {
    int n = i / 288, k = i % 288;
    float ve = (k < 32) ? encWih[n * 32 + k] : encWhh[n * 256 + k - 32];
    float vd = (k < 32) ? decWih[n * 32 + k] : decWhh[n * 256 + k - 32];
    encW[i] = f2bf(ve);
    decW[i] = f2bf(vd);
  }
  if (i < 32 * 256) pW[i] = f2bf(projW[i]);
  if (i < 256) {
    encBias[i]       = encbih[i] + encbhh[i];
    encBias[256 + i] = encbih[256 + i] + encbhh[256 + i];
    encBias[512 + i] = encbih[512 + i];
    encBias[768 + i] = encbhh[512 + i];
    decBias[i]       = decbih[i] + decbhh[i];
    decBias[256 + i] = decbih[256 + i] + decbhh[256 + i];
    decBias[512 + i] = decbih[512 + i];
    decBias[768 + i] = decbhh[512 + i];
  }
  if (i < 32) pB[i] = projB[i];
}

// ---------- persistent GRU seq2seq kernel ----------
// 64 blocks x 1024 threads (16 waves). Block b owns samples [16b, 16b+16).
// Wave w owns gate columns j = w*16 + (lane&15): gate rows {j, j+256, j+512}.
// Per step: gates (16x768) = [x_t | h] (16x288) @ W_cat^T via 27 MFMAs/wave.
// h carried in f32 regs (lane owns h[(lane>>4)*4 + r][j]); bf16 copy in LDS
// feeds A-fragments of all waves.
__global__ __launch_bounds__(1024) void gru_kernel(
    const float* __restrict__ x,
    const unsigned short* __restrict__ encW,
    const unsigned short* __restrict__ decW,
    const unsigned short* __restrict__ pW,
    const float* __restrict__ encBias,
    const float* __restrict__ decBias,
    const float* __restrict__ pB,
    float* __restrict__ out) {
  // strides chosen: 16B-aligned rows, 8 lanes per LDS bank-quad on b128 reads
  __shared__ __align__(16) unsigned short h_lds[16][264];   // h bf16, [sample][k]
  __shared__ __align__(16) unsigned short x_lds[16][40];    // x_t / prev pred bf16
  __shared__ __align__(16) unsigned short pw_lds[32][264];  // proj_W bf16 [n][k]

  const int tid  = (int)threadIdx.x;
  const int wave = tid >> 6;
  const int lane = tid & 63;
  const int l15  = lane & 15;
  const int l4   = lane >> 4;
  const int ko   = l4 * 8;                 // k offset within a 32-chunk
  const int gbase = (int)blockIdx.x * G_;
  const int j    = wave * 16 + l15;        // hidden/gate column 0..255

  for (int i = tid; i < 32 * 256; i += 1024)
    pw_lds[i >> 8][i & 255] = pW[i];
  for (int i = tid; i < 16 * 264; i += 1024)
    ((unsigned short*)h_lds)[i] = 0;
  if (tid < 16 * 40) ((unsigned short*)x_lds)[tid] = 0;

  f32x4 hreg = {0.f, 0.f, 0.f, 0.f};
  const float pbias = (wave < 2) ? pB[wave * 16 + l15] : 0.f;

  for (int phase = 0; phase < 2; ++phase) {
    const unsigned short* W  = phase ? decW : encW;
    const float* bias        = phase ? decBias : encBias;
    const float b_r  = bias[j];
    const float b_z  = bias[256 + j];
    const float b_in = bias[512 + j];
    const float b_hn = bias[768 + j];
    const unsigned short* Wr = W + (size_t)j * 288 + ko;       // row j    (r)
    const unsigned short* Wz = Wr + (size_t)256 * 288;         // row j+256(z)
    const unsigned short* Wn = Wz + (size_t)256 * 288;         // row j+512(n)

    for (int t = 0; t < T_; ++t) {
      if (phase == 0 && tid < 512) {  // stage x_t (encoder input)
        int g = tid >> 5, c = tid & 31;
        x_lds[g][c] = f2bf(x[(size_t)(gbase + g) * (T_ * C_) + t * C_ + c]);
      }
      __syncthreads();  // x_lds/prev + h_lds ready

      f32x4 accr  = {b_r, b_r, b_r, b_r};
      f32x4 accz  = {b_z, b_z, b_z, b_z};
      f32x4 accin = {b_in, b_in, b_in, b_in};  // i_n (x part only)
      f32x4 acchn = {b_hn, b_hn, b_hn, b_hn};  // h_n (h part only)

      {  // k-chunk 0: x / prev-pred part (K=32)
        bf16x8 a0 = *(const bf16x8*)&x_lds[l15][ko];
        bf16x8 br = *(const bf16x8*)(Wr);
        bf16x8 bz = *(const bf16x8*)(Wz);
        bf16x8 bn = *(const bf16x8*)(Wn);
        accr  = MFMA16(a0, br, accr);
        accz  = MFMA16(a0, bz, accz);
        accin = MFMA16(a0, bn, accin);
      }
#pragma unroll
      for (int kk = 1; kk <= 8; ++kk) {  // h part (K=256)
        bf16x8 ah = *(const bf16x8*)&h_lds[l15][(kk - 1) * 32 + ko];
        bf16x8 br = *(const bf16x8*)(Wr + kk * 32);
        bf16x8 bz = *(const bf16x8*)(Wz + kk * 32);
        bf16x8 bn = *(const bf16x8*)(Wn + kk * 32);
        accr  = MFMA16(ah, br, accr);
        accz  = MFMA16(ah, bz, accz);
        acchn = MFMA16(ah, bn, acchn);
      }

      __syncthreads();  // all waves done reading h_lds/x_lds

      // gate math, fully in-register; lane owns h[(l4*4+r)][j]
#pragma unroll
      for (int r = 0; r < 4; ++r) {
        float rg = fsigmoid(accr[r]);
        float zg = fsigmoid(accz[r]);
        float ng = ftanh(accin[r] + rg * acchn[r]);
        float hv = zg * (hreg[r] - ng) + ng;  // (1-z)*n + z*h
        hreg[r] = hv;
        h_lds[l4 * 4 + r][j] = f2bf(hv);
      }

      if (phase == 1) {
        __syncthreads();  // h_lds (new h) ready for projection
        if (wave < 2) {   // pred = h_new @ proj_W^T + proj_b  (16x32, K=256)
          f32x4 acc = {pbias, pbias, pbias, pbias};
#pragma unroll
          for (int kk = 0; kk < 8; ++kk) {
            bf16x8 ah = *(const bf16x8*)&h_lds[l15][kk * 32 + ko];
            bf16x8 bw = *(const bf16x8*)&pw_lds[wave * 16 + l15][kk * 32 + ko];
            acc = MFMA16(ah, bw, acc);
          }
          const int n = wave * 16 + l15;
#pragma unroll
          for (int r = 0; r < 4; ++r) {
            int m = l4 * 4 + r;
            out[(size_t)(gbase + m) * (T_ * C_) + t * C_ + n] = acc[r];
            x_lds[m][n] = f2bf(acc[r]);  // autoregressive input for t+1
          }
        }
      }
    }
    if (phase == 0) {  // decoder start token = zeros
      if (tid < 16 * 40) ((unsigned short*)x_lds)[tid] = 0;
    }
  }
}

extern "C" void kernel_launch(void* const* d_in, const int* in_sizes, int n_in,
                              void* d_out, int out_size, void* d_ws, size_t ws_size,
                              hipStream_t stream) {
  const float* x      = (const float*)d_in[0];
  const float* encWih = (const float*)d_in[1];
  const float* encWhh = (const float*)d_in[2];
  const float* encbih = (const float*)d_in[3];
  const float* encbhh = (const float*)d_in[4];
  const float* decWih = (const float*)d_in[5];
  const float* decWhh = (const float*)d_in[6];
  const float* decbih = (const float*)d_in[7];
  const float* decbhh = (const float*)d_in[8];
  const float* projW  = (const float*)d_in[9];
  const float* projB  = (const float*)d_in[10];

  char* ws = (char*)d_ws;
  unsigned short* encW = (unsigned short*)(ws);             // 768*288*2 = 442368
  unsigned short* decW = (unsigned short*)(ws + 442368);    // 442368
  unsigned short* pW   = (unsigned short*)(ws + 884736);    // 32*256*2 = 16384
  float* encBias = (float*)(ws + 901120);                   // 1024 f32
  float* decBias = (float*)(ws + 905216);                   // 1024 f32
  float* pB      = (float*)(ws + 909312);                   // 32 f32

  pack_kernel<<<864, 256, 0, stream>>>(encWih, encWhh, encbih, encbhh,
                                       decWih, decWhh, decbih, decbhh,
                                       projW, projB,
                                       encW, decW, pW, encBias, decBias, pB);
  gru_kernel<<<64, 1024, 0, stream>>>(x, encW, decW, pW, encBias, decBias, pB,
                                      (float*)d_out);
}